// Round 3
// baseline (814.002 us; speedup 1.0000x reference)
//
#include <hip/hip_runtime.h>

// SNN B=128, D0=512, T=512, dims 1024/1024/512, DECAY=0.5, THRESH=0.3
// Round 14: wide 256-col 8-wave bit-layer for L1 (snn_layer_bits_wide).
//  - BN=256, BK=32, single B buffer (hi/lo 32 KB) + bits 16 KB = 64 KB LDS
//    -> 2 blocks/CU = 16 waves/CU = 4 waves/SIMD (2x r13), lb(512,4).
//  - Theory: barrier-lockstep waves leave the MFMA pipe idle during LDS/VALU
//    phases; more independent resident waves fill it.
//  - L0 (snn_layer0) and L2 (narrow snn_layer_bits) unchanged from r13.
// MFMA sequence per acc element identical to r13 (absmax=0 preserved).

typedef __bf16 bf16;
typedef __attribute__((ext_vector_type(8))) __bf16 bf16x8;
typedef __attribute__((ext_vector_type(16))) float f32x16;
typedef unsigned long long u64;

#define B_   128
#define D0_  512
#define T_   512
#define TS_  128
#define N1_  1024
#define N2_  1024
#define N3_  512
#define MFMA32(a,b,c) __builtin_amdgcn_mfma_f32_32x32x16_bf16((a),(b),(c),0,0,0)

#define GL2LDS(g, l) __builtin_amdgcn_global_load_lds( \
    (const __attribute__((address_space(1))) void*)(g), \
    (__attribute__((address_space(3))) void*)(l), 16, 0, 0)

#define WAIT_BARRIER() do { \
    asm volatile("s_waitcnt vmcnt(0)" ::: "memory"); \
    __builtin_amdgcn_s_barrier(); } while (0)

// ---------- setup ----------

__global__ __launch_bounds__(256)
void split_w(const float* __restrict__ W, bf16* __restrict__ WTh, bf16* __restrict__ WTl,
             int K, int N)
{
    __shared__ float tile[32][33];
    const int k0 = blockIdx.x * 32, n0 = blockIdx.y * 32;
    const int tx = threadIdx.x & 31, ty = threadIdx.x >> 5;
#pragma unroll
    for (int r = 0; r < 4; ++r)
        tile[ty + r * 8][tx] = W[(size_t)(k0 + ty + r * 8) * N + n0 + tx];
    __syncthreads();
#pragma unroll
    for (int r = 0; r < 4; ++r) {
        int nl = ty + r * 8;
        float v = tile[tx][nl];
        bf16 h = (bf16)v;
        size_t o = (size_t)(n0 + nl) * K + k0 + tx;
        WTh[o] = h;
        WTl[o] = (bf16)(v - (float)h);
    }
}

// x [B][D0][T] fp32 -> Xh/Xl slice-major [s][b][tl][D0] bf16 (hi/lo)
__global__ __launch_bounds__(256)
void split_x(const float* __restrict__ in, bf16* __restrict__ Xh, bf16* __restrict__ Xl)
{
    __shared__ float tile[32][33];
    const int b = blockIdx.z, d0 = blockIdx.x * 32, t0 = blockIdx.y * 32;
    const int tx = threadIdx.x & 31, ty = threadIdx.x >> 5;
#pragma unroll
    for (int r = 0; r < 4; ++r)
        tile[ty + r * 8][tx] = in[((size_t)b * D0_ + d0 + ty + r * 8) * T_ + t0 + tx];
    __syncthreads();
    const int s = t0 >> 7;
#pragma unroll
    for (int r = 0; r < 4; ++r) {
        int t  = t0 + ty + r * 8;
        int tl = t & (TS_ - 1);
        float v = tile[tx][ty + r * 8];
        bf16 h = (bf16)v;
        size_t o = (((size_t)s * B_ + b) * TS_ + tl) * D0_ + d0 + tx;
        Xh[o] = h;
        Xl[o] = (bf16)(v - (float)h);
    }
}

// 8 bits -> bf16x8 of {0.0, 1.0} (exact).
__device__ __forceinline__ bf16x8 expand8(unsigned v)
{
    union { unsigned u[4]; bf16x8 h; } r;
    const unsigned p = v * 0x8001u;
#pragma unroll
    for (int i = 0; i < 4; ++i)
        r.u[i] = ((p >> (2 * i)) & 0x10001u) * 0x3F80u;
    return r.h;
}

// ---------- layer 0: Xh/Xl @ W0 (3-term), BK=32, 2-phase dbuf (r13) ----------
__global__ __launch_bounds__(256, 2)
void snn_layer0(const bf16* __restrict__ Ah, const bf16* __restrict__ Al,
                const bf16* __restrict__ WTh, const bf16* __restrict__ WTl,
                u64* __restrict__ bitsOut)
{
    constexpr int K = D0_;
    __shared__ char smem[65536];
    bf16* sA0  = (bf16*)(smem);
    bf16* sAl0 = (bf16*)(smem + 8192);
    bf16* sB0  = (bf16*)(smem + 16384);
    bf16* sBl0 = (bf16*)(smem + 24576);
    bf16* sA1  = (bf16*)(smem + 32768);
    bf16* sAl1 = (bf16*)(smem + 40960);
    bf16* sB1  = (bf16*)(smem + 49152);
    bf16* sBl1 = (bf16*)(smem + 57344);
    float* If  = (float*)smem;

    const int tid = threadIdx.x, lane = tid & 63, w = tid >> 6;
    const int wm = w & 1, wn = w >> 1;
    const int l31 = lane & 31, kh = lane >> 5;
    const int b = blockIdx.x;
    const int nb = blockIdx.y * 128;

    const int i4 = lane >> 2, c4 = lane & 3;
    const int csrc = c4 ^ ((i4 >> 1) & 3);
    const bf16* gBh = WTh + (size_t)(nb + w * 32 + i4) * K + csrc * 8;
    const bf16* gBl = WTl + (size_t)(nb + w * 32 + i4) * K + csrc * 8;
    const int wT = w * 32 * 32;

    int rA[2], rB[2], swA[2], swB[2];
#pragma unroll
    for (int i = 0; i < 2; ++i) {
        rA[i] = wm * 64 + i * 32 + l31;
        rB[i] = wn * 64 + i * 32 + l31;
        swA[i] = (rA[i] >> 1) & 3;
        swB[i] = (rB[i] >> 1) & 3;
    }

    float cm = 0.f, cs = 0.f;
    const int scol = tid & 63;
    float* Ifb = If + (tid >> 6) * 4096;

#define STAGE0(dA, dAl, dBh, dBl, go)                                          \
    do {                                                                       \
        _Pragma("unroll")                                                      \
        for (int inst = 0; inst < 2; ++inst) {                                 \
            GL2LDS(gA  + (size_t)(inst * 16) * K + (go), (dA)  + wT + inst * 16 * 32); \
            GL2LDS(gAl + (size_t)(inst * 16) * K + (go), (dAl) + wT + inst * 16 * 32); \
            GL2LDS(gBh + (size_t)(inst * 16) * K + (go), (dBh) + wT + inst * 16 * 32); \
            GL2LDS(gBl + (size_t)(inst * 16) * K + (go), (dBl) + wT + inst * 16 * 32); \
        }                                                                      \
    } while (0)

#define KSTEP0(cA, cAl, cBh, cBl)                                              \
    do {                                                                       \
        bf16x8 a[2][2], al2[2][2];                                             \
        _Pragma("unroll")                                                      \
        for (int mi = 0; mi < 2; ++mi)                                         \
            _Pragma("unroll")                                                  \
            for (int h = 0; h < 2; ++h) {                                      \
                const int off = rA[mi] * 32 + (((2 * h + kh) ^ swA[mi]) * 8);  \
                a[mi][h]   = *(const bf16x8*)((cA) + off);                     \
                al2[mi][h] = *(const bf16x8*)((cAl) + off);                    \
            }                                                                  \
        _Pragma("unroll")                                                      \
        for (int ni = 0; ni < 2; ++ni) {                                       \
            _Pragma("unroll")                                                  \
            for (int h = 0; h < 2; ++h) {                                      \
                const int off = rB[ni] * 32 + (((2 * h + kh) ^ swB[ni]) * 8);  \
                bf16x8 bh = *(const bf16x8*)((cBh) + off);                     \
                bf16x8 bl = *(const bf16x8*)((cBl) + off);                     \
                _Pragma("unroll")                                              \
                for (int mi = 0; mi < 2; ++mi) {                               \
                    acc[mi][ni] = MFMA32(a[mi][h], bh, acc[mi][ni]);           \
                    acc[mi][ni] = MFMA32(al2[mi][h], bh, acc[mi][ni]);         \
                    acc[mi][ni] = MFMA32(a[mi][h], bl, acc[mi][ni]);           \
                }                                                              \
            }                                                                  \
        }                                                                      \
        WAIT_BARRIER();                                                       \
    } while (0)

#pragma unroll 1
    for (int s = 0; s < T_ / TS_; ++s) {
        const size_t arow = ((size_t)s * B_ + b) * TS_;
        const bf16* gA  = Ah + (arow + w * 32 + i4) * K + csrc * 8;
        const bf16* gAl = Al + (arow + w * 32 + i4) * K + csrc * 8;

        STAGE0(sA0, sAl0, sB0, sBl0, 0);
        WAIT_BARRIER();

        f32x16 acc[2][2] = {};

#pragma unroll 1
        for (int ks = 0; ks < K / 32; ks += 2) {
            STAGE0(sA1, sAl1, sB1, sBl1, (ks + 1) * 32);
            KSTEP0(sA0, sAl0, sB0, sBl0);
            if (ks + 2 < K / 32)
                STAGE0(sA0, sAl0, sB0, sBl0, (ks + 2) * 32);
            KSTEP0(sA1, sAl1, sB1, sBl1);
        }

        u64 word0 = 0, word1 = 0;
        if (wm == 0) {
#pragma unroll
            for (int ni = 0; ni < 2; ++ni)
#pragma unroll
                for (int mi = 0; mi < 2; ++mi)
#pragma unroll
                    for (int r = 0; r < 16; ++r) {
                        const int tt = mi * 32 + (r & 3) + 8 * (r >> 2) + 4 * kh;
                        If[wn * 4096 + tt * 64 + ni * 32 + l31] = acc[mi][ni][r];
                    }
        }
        __syncthreads();
        if (tid < 128) {
            float m = cm, sp = cs;
#pragma unroll 4
            for (int tt = 0; tt < 64; ++tt) {
                m = m * 0.5f * (1.0f - sp) + Ifb[tt * 64 + scol];
                const bool fire = m > 0.3f;
                sp = fire ? 1.0f : 0.0f;
                u64 bal = __ballot(fire);
                if ((tid & 63) == tt) word0 = bal;
            }
            cm = m; cs = sp;
        }
        __syncthreads();
        if (wm == 1) {
#pragma unroll
            for (int ni = 0; ni < 2; ++ni)
#pragma unroll
                for (int mi = 0; mi < 2; ++mi)
#pragma unroll
                    for (int r = 0; r < 16; ++r) {
                        const int tt = mi * 32 + (r & 3) + 8 * (r >> 2) + 4 * kh;
                        If[wn * 4096 + tt * 64 + ni * 32 + l31] = acc[mi][ni][r];
                    }
        }
        __syncthreads();
        if (tid < 128) {
            float m = cm, sp = cs;
#pragma unroll 4
            for (int tt = 0; tt < 64; ++tt) {
                m = m * 0.5f * (1.0f - sp) + Ifb[tt * 64 + scol];
                const bool fire = m > 0.3f;
                sp = fire ? 1.0f : 0.0f;
                u64 bal = __ballot(fire);
                if ((tid & 63) == tt) word1 = bal;
            }
            cm = m; cs = sp;
            u64* dst = bitsOut + ((size_t)s * B_ + b) * 2048;
            const int j8 = (nb >> 6) + (tid >> 6);
            const int t0 = tid & 63, t1 = 64 + (tid & 63);
            dst[t0 * 16 + (j8 ^ (t0 & 15))] = word0;
            dst[t1 * 16 + (j8 ^ (t1 & 15))] = word1;
        }
        __syncthreads();
    }
#undef STAGE0
#undef KSTEP0
}

// ---------- narrow bit-layer (r13), used for L2 ----------
template<bool WRITE_BITS>
__global__ __launch_bounds__(256, 2)
void snn_layer_bits(const u64* __restrict__ bitsIn,
                    const bf16* __restrict__ WTh, const bf16* __restrict__ WTl,
                    u64* __restrict__ bitsOut, float* __restrict__ outp, int N)
{
    constexpr int K = 1024;
    __shared__ char smem[81920];
    char* bitsLds = smem;
    bf16* sBh0 = (bf16*)(smem + 16384);
    bf16* sBl0 = (bf16*)(smem + 32768);
    bf16* sBh1 = (bf16*)(smem + 49152);
    bf16* sBl1 = (bf16*)(smem + 65536);
    float* If  = (float*)(smem + 16384);

    const int tid = threadIdx.x, lane = tid & 63, w = tid >> 6;
    const int wm = w & 1, wn = w >> 1;
    const int l31 = lane & 31, kh = lane >> 5;
    const int b = blockIdx.x;
    const int nb = blockIdx.y * 128;

    const int i8 = lane >> 3, c8 = lane & 7;
    const bf16* gBh = WTh + (size_t)(nb + w * 32 + i8) * K + (c8 ^ i8) * 8;
    const bf16* gBl = WTl + (size_t)(nb + w * 32 + i8) * K + (c8 ^ i8) * 8;
    const int wB = w * 32 * 64;

    int rA[2], rB[2];
#pragma unroll
    for (int i = 0; i < 2; ++i) {
        rA[i] = wm * 64 + i * 32 + l31;
        rB[i] = wn * 64 + i * 32 + l31;
    }
    const int sw7 = l31 & 7, sw15 = l31 & 15, sh8 = 8 * kh;

    float cm = 0.f, cs = 0.f;
    const int scol = tid & 63;
    float* Ifb = If + (tid >> 6) * 4096;

#define STAGEB(dBh, dBl, go)                                                   \
    do {                                                                       \
        _Pragma("unroll")                                                      \
        for (int inst = 0; inst < 4; ++inst) {                                 \
            GL2LDS(gBh + (size_t)(inst * 8) * K + (go), (dBh) + wB + inst * 8 * 64); \
            GL2LDS(gBl + (size_t)(inst * 8) * K + (go), (dBl) + wB + inst * 8 * 64); \
        }                                                                      \
    } while (0)

#define KSTEPB(ks, cBh, cBl)                                                   \
    do {                                                                       \
        u64 wA0 = *(const u64*)(bitsLds + rA[0] * 128 + (((ks) ^ sw15) << 3)) >> sh8; \
        u64 wA1 = *(const u64*)(bitsLds + rA[1] * 128 + (((ks) ^ sw15) << 3)) >> sh8; \
        _Pragma("unroll")                                                      \
        for (int h = 0; h < 4; ++h) {                                          \
            bf16x8 a0 = expand8((unsigned)(wA0 >> (16 * h)) & 0xFFu);          \
            bf16x8 a1 = expand8((unsigned)(wA1 >> (16 * h)) & 0xFFu);          \
            _Pragma("unroll")                                                  \
            for (int ni = 0; ni < 2; ++ni) {                                   \
                const int off = rB[ni] * 64 + (((2 * h + kh) ^ sw7) << 3);     \
                bf16x8 bh = *(const bf16x8*)((cBh) + off);                     \
                bf16x8 bl = *(const bf16x8*)((cBl) + off);                     \
                acc[0][ni] = MFMA32(a0, bh, acc[0][ni]);                       \
                acc[0][ni] = MFMA32(a0, bl, acc[0][ni]);                       \
                acc[1][ni] = MFMA32(a1, bh, acc[1][ni]);                       \
                acc[1][ni] = MFMA32(a1, bl, acc[1][ni]);                       \
            }                                                                  \
        }                                                                      \
        WAIT_BARRIER();                                                       \
    } while (0)

#pragma unroll 1
    for (int s = 0; s < T_ / TS_; ++s) {
        {
            const char* src = (const char*)bitsIn + ((size_t)s * B_ + b) * 16384;
#pragma unroll
            for (int i = 0; i < 4; ++i)
                GL2LDS(src + (w * 4 + i) * 1024 + lane * 16,
                       bitsLds + (w * 4 + i) * 1024);
        }
        STAGEB(sBh0, sBl0, 0);
        WAIT_BARRIER();

        f32x16 acc[2][2] = {};

#pragma unroll 1
        for (int ks = 0; ks < K / 64; ks += 2) {
            STAGEB(sBh1, sBl1, (ks + 1) * 64);
            KSTEPB(ks, sBh0, sBl0);
            if (ks + 2 < K / 64)
                STAGEB(sBh0, sBl0, (ks + 2) * 64);
            KSTEPB(ks + 1, sBh1, sBl1);
        }

        u64 word0 = 0, word1 = 0;
        if (wm == 0) {
#pragma unroll
            for (int ni = 0; ni < 2; ++ni)
#pragma unroll
                for (int mi = 0; mi < 2; ++mi)
#pragma unroll
                    for (int r = 0; r < 16; ++r) {
                        const int tt = mi * 32 + (r & 3) + 8 * (r >> 2) + 4 * kh;
                        If[wn * 4096 + tt * 64 + ni * 32 + l31] = acc[mi][ni][r];
                    }
        }
        __syncthreads();
        if (tid < 128) {
            float m = cm, sp = cs;
#pragma unroll 4
            for (int tt = 0; tt < 64; ++tt) {
                m = m * 0.5f * (1.0f - sp) + Ifb[tt * 64 + scol];
                const bool fire = m > 0.3f;
                sp = fire ? 1.0f : 0.0f;
                if constexpr (WRITE_BITS) {
                    u64 bal = __ballot(fire);
                    if ((tid & 63) == tt) word0 = bal;
                }
            }
            cm = m; cs = sp;
        }
        __syncthreads();
        if (wm == 1) {
#pragma unroll
            for (int ni = 0; ni < 2; ++ni)
#pragma unroll
                for (int mi = 0; mi < 2; ++mi)
#pragma unroll
                    for (int r = 0; r < 16; ++r) {
                        const int tt = mi * 32 + (r & 3) + 8 * (r >> 2) + 4 * kh;
                        If[wn * 4096 + tt * 64 + ni * 32 + l31] = acc[mi][ni][r];
                    }
        }
        __syncthreads();
        if (tid < 128) {
            float m = cm, sp = cs;
#pragma unroll 4
            for (int tt = 0; tt < 64; ++tt) {
                m = m * 0.5f * (1.0f - sp) + Ifb[tt * 64 + scol];
                const bool fire = m > 0.3f;
                sp = fire ? 1.0f : 0.0f;
                if constexpr (WRITE_BITS) {
                    u64 bal = __ballot(fire);
                    if ((tid & 63) == tt) word1 = bal;
                }
            }
            cm = m; cs = sp;
            if constexpr (WRITE_BITS) {
                u64* dst = bitsOut + ((size_t)s * B_ + b) * 2048;
                const int j8 = (nb >> 6) + (tid >> 6);
                const int t0 = tid & 63, t1 = 64 + (tid & 63);
                dst[t0 * 16 + (j8 ^ (t0 & 15))] = word0;
                dst[t1 * 16 + (j8 ^ (t1 & 15))] = word1;
            } else {
                if (s == T_ / TS_ - 1)
                    outp[(size_t)b * N + nb + tid] = cs;
            }
        }
        __syncthreads();
    }
#undef STAGEB
#undef KSTEPB
}

// ---------- wide bit-layer: BN=256, 8 waves, BK=32, 64 KB LDS ----------
// 2 blocks/CU -> 4 waves/SIMD. Used for L1.
template<bool WRITE_BITS>
__global__ __launch_bounds__(512, 4)
void snn_layer_bits_wide(const u64* __restrict__ bitsIn,
                         const bf16* __restrict__ WTh, const bf16* __restrict__ WTl,
                         u64* __restrict__ bitsOut, float* __restrict__ outp, int N)
{
    constexpr int K = 1024;
    __shared__ char smem[65536];
    char* bitsLds = smem;                      // [0,16K): bit tile [128 t][128 B]
    bf16* sBh = (bf16*)(smem + 16384);         // [16K,32K): B hi [256 n][32 k]
    bf16* sBl = (bf16*)(smem + 32768);         // [32K,48K): B lo
    float* If = (float*)smem;                  // epilogue overlay, full 64 KB

    const int tid = threadIdx.x, lane = tid & 63, w = tid >> 6;  // w in 0..7
    const int wm = w & 1, wn = w >> 1;         // wm: row half, wn in 0..3: col quad
    const int l31 = lane & 31, kh = lane >> 5;
    const int b = blockIdx.x;
    const int nb = blockIdx.y * 256;

    // B staging (BK=32): per wave 2 insts of 16 rows x 64 B each, rows
    // {inst*128 + w*16 + i4}; chunk pre-swizzled with key (row>>1)&3 = (i4>>1)&3.
    const int i4 = lane >> 2, c4 = lane & 3;
    const int csrc = c4 ^ ((i4 >> 1) & 3);
    const bf16* gBh0 = WTh + (size_t)(nb + w * 16 + i4) * K + csrc * 8;
    const bf16* gBh1 = WTh + (size_t)(nb + 128 + w * 16 + i4) * K + csrc * 8;
    const bf16* gBl0 = WTl + (size_t)(nb + w * 16 + i4) * K + csrc * 8;
    const bf16* gBl1 = WTl + (size_t)(nb + 128 + w * 16 + i4) * K + csrc * 8;
    const int dB0 = (w * 16) * 32;             // LDS element offset, rows w*16..
    const int dB1 = (128 + w * 16) * 32;

    int rA[2], rB[2], swB[2];
#pragma unroll
    for (int i = 0; i < 2; ++i) {
        rA[i] = wm * 64 + i * 32 + l31;        // A rows (t), in [0,128)
        rB[i] = wn * 64 + i * 32 + l31;        // B rows (n), in [0,256)
        swB[i] = (rB[i] >> 1) & 3;
    }
    const int sh8 = 8 * kh;
    const int bA0 = rA[0] * 128, bA1 = rA[1] * 128;
    const int s15a = rA[0] & 15, s15b = rA[1] & 15;

    float cm = 0.f, cs = 0.f;                  // LIF carry, col = nb + tid (tid<256)

#define STAGEW(go)                                                             \
    do {                                                                       \
        GL2LDS(gBh0 + (go), sBh + dB0);                                        \
        GL2LDS(gBh1 + (go), sBh + dB1);                                        \
        GL2LDS(gBl0 + (go), sBl + dB0);                                        \
        GL2LDS(gBl1 + (go), sBl + dB1);                                        \
    } while (0)

// one BK=32 step; wa0/wa1 = 32-bit halves of the bits u64 for rows rA[0],rA[1]
#define KSTEPW(wa0, wa1)                                                       \
    do {                                                                       \
        _Pragma("unroll")                                                      \
        for (int h = 0; h < 2; ++h) {                                          \
            bf16x8 a0 = expand8(((wa0) >> (16 * h + sh8)) & 0xFFu);            \
            bf16x8 a1 = expand8(((wa1) >> (16 * h + sh8)) & 0xFFu);            \
            _Pragma("unroll")                                                  \
            for (int ni = 0; ni < 2; ++ni) {                                   \
                const int off = rB[ni] * 32 + (((2 * h + kh) ^ swB[ni]) * 8);  \
                bf16x8 bh = *(const bf16x8*)(sBh + off);                       \
                bf16x8 bl = *(const bf16x8*)(sBl + off);                       \
                acc[0][ni] = MFMA32(a0, bh, acc[0][ni]);                       \
                acc[0][ni] = MFMA32(a0, bl, acc[0][ni]);                       \
                acc[1][ni] = MFMA32(a1, bh, acc[1][ni]);                       \
                acc[1][ni] = MFMA32(a1, bl, acc[1][ni]);                       \
            }                                                                  \
        }                                                                      \
    } while (0)

#pragma unroll 1
    for (int s = 0; s < T_ / TS_; ++s) {
        // slice prologue: stage bit tile (2 KB/wave) + B(ks=0)
        {
            const char* src = (const char*)bitsIn + ((size_t)s * B_ + b) * 16384;
            GL2LDS(src + w * 2048 + lane * 16, bitsLds + w * 2048);
            GL2LDS(src + w * 2048 + 1024 + lane * 16, bitsLds + w * 2048 + 1024);
        }
        STAGEW(0);
        WAIT_BARRIER();

        f32x16 acc[2][2] = {};

#pragma unroll 1
        for (int ks = 0; ks < K / 32; ks += 2) {
            const int j8 = ks >> 1;
            const u64 w0 = *(const u64*)(bitsLds + bA0 + ((j8 ^ s15a) << 3));
            const u64 w1 = *(const u64*)(bitsLds + bA1 + ((j8 ^ s15b) << 3));

            KSTEPW((unsigned)w0, (unsigned)w1);              // step ks
            __builtin_amdgcn_s_barrier();                    // reads done
            STAGEW((ks + 1) * 32);
            WAIT_BARRIER();                                  // B(ks+1) ready

            KSTEPW((unsigned)(w0 >> 32), (unsigned)(w1 >> 32));  // step ks+1
            __builtin_amdgcn_s_barrier();
            if (ks + 2 < K / 32)
                STAGEW((ks + 2) * 32);
            WAIT_BARRIER();
        }

        // ---- epilogue: 2-phase LIF scan over full 64 KB If overlay ----
        u64 word0 = 0, word1 = 0;
        if (wm == 0) {                         // dump t 0..63, all 256 cols
#pragma unroll
            for (int ni = 0; ni < 2; ++ni)
#pragma unroll
                for (int mi = 0; mi < 2; ++mi)
#pragma unroll
                    for (int r = 0; r < 16; ++r) {
                        const int tt = mi * 32 + (r & 3) + 8 * (r >> 2) + 4 * kh;
                        If[tt * 256 + wn * 64 + ni * 32 + l31] = acc[mi][ni][r];
                    }
        }
        __syncthreads();
        if (tid < 256) {                       // scan t 0..63, col = nb + tid
            float m = cm, sp = cs;
#pragma unroll 4
            for (int tt = 0; tt < 64; ++tt) {
                m = m * 0.5f * (1.0f - sp) + If[tt * 256 + tid];
                const bool fire = m > 0.3f;
                sp = fire ? 1.0f : 0.0f;
                if constexpr (WRITE_BITS) {
                    u64 bal = __ballot(fire);
                    if ((tid & 63) == tt) word0 = bal;
                }
            }
            cm = m; cs = sp;
        }
        __syncthreads();
        if (wm == 1) {                         // dump t 64..127
#pragma unroll
            for (int ni = 0; ni < 2; ++ni)
#pragma unroll
                for (int mi = 0; mi < 2; ++mi)
#pragma unroll
                    for (int r = 0; r < 16; ++r) {
                        const int tt = mi * 32 + (r & 3) + 8 * (r >> 2) + 4 * kh;
                        If[tt * 256 + wn * 64 + ni * 32 + l31] = acc[mi][ni][r];
                    }
        }
        __syncthreads();
        if (tid < 256) {                       // scan t 64..127
            float m = cm, sp = cs;
#pragma unroll 4
            for (int tt = 0; tt < 64; ++tt) {
                m = m * 0.5f * (1.0f - sp) + If[tt * 256 + tid];
                const bool fire = m > 0.3f;
                sp = fire ? 1.0f : 0.0f;
                if constexpr (WRITE_BITS) {
                    u64 bal = __ballot(fire);
                    if ((tid & 63) == tt) word1 = bal;
                }
            }
            cm = m; cs = sp;
            if constexpr (WRITE_BITS) {
                u64* dst = bitsOut + ((size_t)s * B_ + b) * 2048;
                const int j8 = (nb >> 6) + (tid >> 6);     // tid>>6 in 0..3
                const int t0 = tid & 63, t1 = 64 + (tid & 63);
                dst[t0 * 16 + (j8 ^ (t0 & 15))] = word0;
                dst[t1 * 16 + (j8 ^ (t1 & 15))] = word1;
            } else {
                if (s == T_ / TS_ - 1)
                    outp[(size_t)b * N + nb + tid] = cs;
            }
        }
        __syncthreads();                       // protect LDS before next slice
    }
#undef STAGEW
#undef KSTEPW
}

extern "C" void kernel_launch(void* const* d_in, const int* in_sizes, int n_in,
                              void* d_out, int out_size, void* d_ws, size_t ws_size,
                              hipStream_t stream)
{
    const float* x  = (const float*)d_in[0];
    const float* w0 = (const float*)d_in[1];
    const float* w1 = (const float*)d_in[2];
    const float* w2 = (const float*)d_in[3];
    float* out = (float*)d_out;

    char* p = (char*)d_ws;
    bf16* w0h = (bf16*)p;  p += (size_t)N1_ * D0_ * 2;
    bf16* w0l = (bf16*)p;  p += (size_t)N1_ * D0_ * 2;
    bf16* w1h = (bf16*)p;  p += (size_t)N2_ * N1_ * 2;
    bf16* w1l = (bf16*)p;  p += (size_t)N2_ * N1_ * 2;
    bf16* w2h = (bf16*)p;  p += (size_t)N3_ * N2_ * 2;
    bf16* w2l = (bf16*)p;  p += (size_t)N3_ * N2_ * 2;
    bf16* Xh  = (bf16*)p;  p += (size_t)T_ * B_ * D0_ * 2;
    bf16* Xl  = (bf16*)p;  p += (size_t)T_ * B_ * D0_ * 2;
    u64* bits0 = (u64*)p;  p += (size_t)(T_/TS_) * B_ * TS_ * (N1_/8);
    u64* bits1 = (u64*)p;  p += (size_t)(T_/TS_) * B_ * TS_ * (N2_/8);

    split_w<<<dim3(D0_/32, N1_/32), 256, 0, stream>>>(w0, w0h, w0l, D0_, N1_);
    split_w<<<dim3(N1_/32, N2_/32), 256, 0, stream>>>(w1, w1h, w1l, N1_, N2_);
    split_w<<<dim3(N2_/32, N3_/32), 256, 0, stream>>>(w2, w2h, w2l, N2_, N3_);
    split_x<<<dim3(D0_/32, T_/32, B_), 256, 0, stream>>>(x, Xh, Xl);

    // L0: X@w0 (3-term split) + LIF -> bit train
    snn_layer0<<<dim3(B_, N1_/128), 256, 0, stream>>>(Xh, Xl, w0h, w0l, bits0);
    // L1: bits0@w1 + LIF -> bit train (wide 256-col, 8-wave)
    snn_layer_bits_wide<true><<<dim3(B_, N2_/256), 512, 0, stream>>>(
        bits0, w1h, w1l, bits1, nullptr, N2_);
    // L2: bits1@w2 + LIF -> final spikes (narrow)
    snn_layer_bits<false><<<dim3(B_, N3_/128), 256, 0, stream>>>(
        bits1, w2h, w2l, nullptr, out, N3_);
}